// Round 9
// baseline (202.626 us; speedup 1.0000x reference)
//
#include <hip/hip_runtime.h>
#include <math.h>

// Problem constants
constexpr int B  = 8;
constexpr int C  = 256;
constexpr int C8 = 32;
constexpr int L  = 2048;

typedef short v8s  __attribute__((ext_vector_type(8)));   // 8 bf16 (4 VGPRs)
typedef float f32x4 __attribute__((ext_vector_type(4)));  // MFMA accumulator

// round-to-nearest-even fp32 -> bf16 (as ushort); inputs finite here
__device__ inline unsigned short f2bf(float f) {
    unsigned u = __builtin_bit_cast(unsigned, f);
    u += 0x7fffu + ((u >> 16) & 1u);
    return (unsigned short)(u >> 16);
}
__device__ inline unsigned packbf(float a, float b) {
    return (unsigned)f2bf(a) | ((unsigned)f2bf(b) << 16);
}

// ---------------------------------------------------------------------------
// Fused Q/K/V projection via MFMA (no separate W-convert kernel: W loaded
// fp32, RNE-packed to bf16 in-register, prefetched one kk ahead).
// Grid: 1024 blocks = (b, 16-wide l tile), 256 thr (4 waves).
// LDS: x,y tiles transposed to [l][c'] bf16, 16B-chunk XOR swizzle.
// Wave w owns 5 output 16-row tiles: k5=0 -> Q (w0,w1, input x) / K (w2,w3,
// input y); k5=1..4 -> V rows (w+4*(k5-1))*16 (input y).
// MFMA 16x16x32, layouts HW-validated rounds 4/5/8.
// ---------------------------------------------------------------------------
__global__ __launch_bounds__(256, 4)
void proj_kernel3(const float* __restrict__ Wq, const float* __restrict__ bq,
                  const float* __restrict__ Wk, const float* __restrict__ bk,
                  const float* __restrict__ Wv, const float* __restrict__ bv,
                  const float* __restrict__ x,  const float* __restrict__ y,
                  unsigned short* __restrict__ Qt, unsigned short* __restrict__ Kt,
                  unsigned short* __restrict__ V) {
    const int blk  = blockIdx.x;
    const int b    = blk >> 7;            // 128 l-tiles per batch
    const int l0   = (blk & 127) * 16;
    const int t    = threadIdx.x;
    const int lane = t & 63;
    const int w    = t >> 6;              // 0..3
    const int g    = lane >> 4;           // 0..3
    const int l15  = lane & 15;

    __shared__ __align__(16) unsigned short xt[16][256];   // 8 KB
    __shared__ __align__(16) unsigned short yt[16][256];   // 8 KB

    const float* xb = x + (size_t)b * C * L;
    const float* yb = y + (size_t)b * C * L;

    // ---- stage: fp32 global -> bf16 LDS, transposed + chunk-swizzled ----
#pragma unroll
    for (int r = 0; r < 4; ++r) {
        int v  = t + 256 * r;             // 0..1023
        int c  = v >> 2;                  // input channel 0..255
        int l2 = (v & 3) * 4;             // l offset {0,4,8,12}
        float4 xv = *(const float4*)(xb + (size_t)c * L + l0 + l2);
        float4 yv = *(const float4*)(yb + (size_t)c * L + l0 + l2);
        float xa[4] = {xv.x, xv.y, xv.z, xv.w};
        float ya[4] = {yv.x, yv.y, yv.z, yv.w};
#pragma unroll
        for (int i = 0; i < 4; ++i) {
            int row = l2 + i;             // 0..15
            int idx = (((c >> 3) ^ row) << 3) | (c & 7);
            xt[row][idx] = f2bf(xa[i]);
            yt[row][idx] = f2bf(ya[i]);
        }
    }

    // ---- W row pointers (independent of kk) ----
    const float* wrow[5];
    {
        const float* w0 = (w < 2) ? Wq : Wk;
        wrow[0] = w0 + (size_t)((w & 1) * 16 + l15) * 256;
#pragma unroll
        for (int k5 = 1; k5 < 5; ++k5)
            wrow[k5] = Wv + (size_t)((w + 4 * (k5 - 1)) * 16 + l15) * 256;
    }

    f32x4 acc[5];
#pragma unroll
    for (int k5 = 0; k5 < 5; ++k5) { f32x4 z = {0.f,0.f,0.f,0.f}; acc[k5] = z; }

    // ---- preload + pack W for kk = 0 ----
    v8s afc[5];
#pragma unroll
    for (int k5 = 0; k5 < 5; ++k5) {
        float4 a0 = *(const float4*)(wrow[k5] + 8 * g);
        float4 a1 = *(const float4*)(wrow[k5] + 8 * g + 4);
        union { unsigned u[4]; v8s v; } pk;
        pk.u[0] = packbf(a0.x, a0.y); pk.u[1] = packbf(a0.z, a0.w);
        pk.u[2] = packbf(a1.x, a1.y); pk.u[3] = packbf(a1.z, a1.w);
        afc[k5] = pk.v;
    }

    __syncthreads();

    // ---- MFMA main loop (W prefetched one kk ahead) ----
#pragma unroll
    for (int kk = 0; kk < 8; ++kk) {
        float4 wl[5][2];
        if (kk < 7) {
#pragma unroll
            for (int k5 = 0; k5 < 5; ++k5) {
                wl[k5][0] = *(const float4*)(wrow[k5] + (kk + 1) * 32 + 8 * g);
                wl[k5][1] = *(const float4*)(wrow[k5] + (kk + 1) * 32 + 8 * g + 4);
            }
        }
        const int boff = l15 * 256 + (((4 * kk + g) ^ l15) << 3);
        v8s by = *(const v8s*)(&yt[0][0] + boff);
        v8s bsel = by;
        if (w < 2) bsel = *(const v8s*)(&xt[0][0] + boff);
        acc[0] = __builtin_amdgcn_mfma_f32_16x16x32_bf16(afc[0], bsel, acc[0], 0, 0, 0);
#pragma unroll
        for (int k5 = 1; k5 < 5; ++k5)
            acc[k5] = __builtin_amdgcn_mfma_f32_16x16x32_bf16(afc[k5], by, acc[k5], 0, 0, 0);
        if (kk < 7) {
#pragma unroll
            for (int k5 = 0; k5 < 5; ++k5) {
                union { unsigned u[4]; v8s v; } pk;
                pk.u[0] = packbf(wl[k5][0].x, wl[k5][0].y);
                pk.u[1] = packbf(wl[k5][0].z, wl[k5][0].w);
                pk.u[2] = packbf(wl[k5][1].x, wl[k5][1].y);
                pk.u[3] = packbf(wl[k5][1].z, wl[k5][1].w);
                afc[k5] = pk.v;
            }
        }
    }

    // ---- epilogue: bias + store bf16 ----
    // D layout: col = l15 (-> l), row = 4g+r (-> out channel within tile)
    {   // k5 = 0: Q or K, transposed store [b][l][32], one 8B store
        int clbase = (w & 1) * 16;
        const float* bias = (w < 2) ? bq : bk;
        unsigned short* dst = (w < 2) ? Qt : Kt;
        float4 b4 = *(const float4*)(bias + clbase + 4 * g);
        int l = l0 + l15;
        unsigned* dp = (unsigned*)(dst + ((size_t)b * L + l) * C8 + clbase + 4 * g);
        dp[0] = packbf(acc[0][0] + b4.x, acc[0][1] + b4.y);
        dp[1] = packbf(acc[0][2] + b4.z, acc[0][3] + b4.w);
    }
#pragma unroll
    for (int k5 = 1; k5 < 5; ++k5) {
        int cl0 = (w + 4 * (k5 - 1)) * 16 + 4 * g;
        float4 b4 = *(const float4*)(bv + cl0);
        float barr[4] = {b4.x, b4.y, b4.z, b4.w};
        int l = l0 + l15;
#pragma unroll
        for (int r = 0; r < 4; ++r)
            V[((size_t)b * C + cl0 + r) * L + l] = f2bf(acc[k5][r] + barr[r]);
    }
}

// ---------------------------------------------------------------------------
// Single-pass MFMA attention, no max-subtraction (shift-invariant softmax;
// |e| <~ 20 -> exp <= ~5e8, safe in fp32/bf16). Grid: 512 blocks = (b,
// 32-row i-tile), XCD-bijective swizzle (each XCD owns one batch -> V[b]
// = 1 MB L2-resident). 512 thr = 8 waves. j-step = 128 (16 steps):
//   wave w: QK^T strip j in [j0+16w, +16) x all 32 i (2 MFMAs, E_T=mfma(K,Q),
//   lane holds E_T[16w+4g+r][i2*16+l15]); P=exp(e) -> bf16 -> XOR-swizzled
//   P tile [32][128] (dbuf, 1 barrier/step). V-frags (indep of P) prefetched
//   at step top; next kf prefetched pre-barrier. PV: wave w owns c-slice
//   [32w,32w+32): 16 MFMAs under setprio(1). Epilogue: out = x + g*acc/S.
// ---------------------------------------------------------------------------
__global__ __launch_bounds__(512, 4)
void attn_kernel4(const unsigned short* __restrict__ Qt,   // [B][L][32] bf16
                  const unsigned short* __restrict__ Kt,   // [B][L][32] bf16
                  const unsigned short* __restrict__ Vw,   // [B][C][L] bf16
                  const float* __restrict__ x,
                  const float* __restrict__ gamma,
                  float* __restrict__ out) {
    const int d       = blockIdx.x;
    const int logical = (d & 7) * 64 + (d >> 3);   // XCD k -> batch k
    const int b       = logical >> 6;
    const int i0      = (logical & 63) * 32;
    const int t    = threadIdx.x;
    const int lane = t & 63;
    const int w    = t >> 6;              // 0..7
    const int g    = lane >> 4;           // 0..3
    const int l15  = lane & 15;

    // P tile: 32 rows x 256 B (16 chunks of 16 B), chunk' = chunk ^ (row&15)
    __shared__ __align__(16) unsigned short Pt[2][32 * 128];  // 2 x 8 KB
    __shared__ float redS[32][33];
    __shared__ float Sf[32];

    const unsigned short* Qb = Qt + (size_t)b * L * C8;
    const unsigned short* Kb = Kt + (size_t)b * L * C8;
    const unsigned short* Vb = Vw + (size_t)b * C * L;

    const v8s qf0 = *(const v8s*)(Qb + (size_t)(i0 + l15) * C8 + 8 * g);
    const v8s qf1 = *(const v8s*)(Qb + (size_t)(i0 + 16 + l15) * C8 + 8 * g);

    f32x4 acc[2][2];
#pragma unroll
    for (int ct = 0; ct < 2; ++ct)
#pragma unroll
        for (int i2 = 0; i2 < 2; ++i2) { f32x4 z = {0.f,0.f,0.f,0.f}; acc[ct][i2] = z; }
    float s0 = 0.f, s1 = 0.f;

    v8s kf = *(const v8s*)(Kb + (size_t)(w * 16 + l15) * C8 + 8 * g);

    int sidx = 0;
#pragma unroll 2
    for (int jt = 0; jt < 16; ++jt, sidx ^= 1) {
        const int j0 = jt * 128;

        // ---- V prefetch (independent of P; hides L2 latency under QK/exp)
        v8s vf[2][4];
#pragma unroll
        for (int ct = 0; ct < 2; ++ct)
#pragma unroll
            for (int kk = 0; kk < 4; ++kk)
                vf[ct][kk] = *(const v8s*)(Vb + (size_t)(w * 32 + ct * 16 + l15) * L
                                           + j0 + kk * 32 + 8 * g);

        // ---- QK^T: wave strip j [16w,16w+16) x both i-subtiles ----
        f32x4 z = {0.f, 0.f, 0.f, 0.f};
        f32x4 e0 = __builtin_amdgcn_mfma_f32_16x16x32_bf16(kf, qf0, z, 0, 0, 0);
        f32x4 e1 = __builtin_amdgcn_mfma_f32_16x16x32_bf16(kf, qf1, z, 0, 0, 0);

        // ---- next-step K prefetch ----
        v8s kfn = kf;
        if (jt < 15)
            kfn = *(const v8s*)(Kb + (size_t)(j0 + 128 + w * 16 + l15) * C8 + 8 * g);

        // ---- P = exp(e) -> bf16 -> swizzled P tile; running sums ----
        char* pbase = (char*)&Pt[0][0] + sidx * (32 * 128 * 2);
        {
            float p0 = __expf(e0[0]), p1 = __expf(e0[1]);
            float p2 = __expf(e0[2]), p3 = __expf(e0[3]);
            s0 += (p0 + p1) + (p2 + p3);
            int chunk = (2 * w + (g >> 1)) ^ l15;
            unsigned* dst = (unsigned*)(pbase + l15 * 256 + chunk * 16 + (g & 1) * 8);
            dst[0] = packbf(p0, p1); dst[1] = packbf(p2, p3);
        }
        {
            float p0 = __expf(e1[0]), p1 = __expf(e1[1]);
            float p2 = __expf(e1[2]), p3 = __expf(e1[3]);
            s1 += (p0 + p1) + (p2 + p3);
            int chunk = (2 * w + (g >> 1)) ^ l15;
            unsigned* dst = (unsigned*)(pbase + (16 + l15) * 256 + chunk * 16 + (g & 1) * 8);
            dst[0] = packbf(p0, p1); dst[1] = packbf(p2, p3);
        }
        __syncthreads();   // P[sidx] complete; dbuf -> one barrier/step safe

        // ---- PV: wave w owns c in [32w, 32w+32) ----
        v8s pf[2][4];
#pragma unroll
        for (int i2 = 0; i2 < 2; ++i2)
#pragma unroll
            for (int kk = 0; kk < 4; ++kk)
                pf[i2][kk] = *(const v8s*)(pbase + (i2 * 16 + l15) * 256
                                           + (((4 * kk + g) ^ l15) << 4));

        __builtin_amdgcn_s_setprio(1);
#pragma unroll
        for (int ct = 0; ct < 2; ++ct)
#pragma unroll
            for (int kk = 0; kk < 4; ++kk) {
                acc[ct][0] = __builtin_amdgcn_mfma_f32_16x16x32_bf16(vf[ct][kk], pf[0][kk], acc[ct][0], 0, 0, 0);
                acc[ct][1] = __builtin_amdgcn_mfma_f32_16x16x32_bf16(vf[ct][kk], pf[1][kk], acc[ct][1], 0, 0, 0);
            }
        __builtin_amdgcn_s_setprio(0);
        kf = kfn;
    }

    // ---- combine row sums: S[i] over 32 (w,g) partials ----
    redS[l15][w * 4 + g]      = s0;
    redS[16 + l15][w * 4 + g] = s1;
    __syncthreads();
    if (t < 32) {
        float S = 0.f;
#pragma unroll
        for (int p = 0; p < 32; ++p) S += redS[t][p];
        Sf[t] = 1.f / S;
    }
    __syncthreads();

    // ---- epilogue: out = x + gamma * acc / S ----
    const float gam  = gamma[0];
    const float inv0 = Sf[l15];
    const float inv1 = Sf[16 + l15];
#pragma unroll
    for (int ct = 0; ct < 2; ++ct)
#pragma unroll
        for (int i2 = 0; i2 < 2; ++i2) {
            const float inv = (i2 == 0) ? inv0 : inv1;
#pragma unroll
            for (int r = 0; r < 4; ++r) {
                int c = w * 32 + ct * 16 + 4 * g + r;   // D row -> channel
                int i = i0 + i2 * 16 + l15;             // D col -> position
                size_t off = ((size_t)b * C + c) * L + i;
                out[off] = x[off] + gam * inv * acc[ct][i2][r];
            }
        }
}

// ---------------------------------------------------------------------------
extern "C" void kernel_launch(void* const* d_in, const int* in_sizes, int n_in,
                              void* d_out, int out_size, void* d_ws, size_t ws_size,
                              hipStream_t stream) {
    const float* x     = (const float*)d_in[0];
    const float* y     = (const float*)d_in[1];
    const float* Wq    = (const float*)d_in[2];
    const float* bq    = (const float*)d_in[3];
    const float* Wk    = (const float*)d_in[4];
    const float* bk    = (const float*)d_in[5];
    const float* Wv    = (const float*)d_in[6];
    const float* bv    = (const float*)d_in[7];
    const float* gamma = (const float*)d_in[8];
    float* out = (float*)d_out;

    unsigned short* wsu = (unsigned short*)d_ws;
    unsigned short* Qt  = wsu;                    // 524288 bf16 (1 MB)
    unsigned short* KtW = wsu + 524288;           // 524288 bf16 (1 MB)
    unsigned short* Vws = wsu + 1048576;          // 4194304 bf16 (8 MB)

    proj_kernel3<<<dim3(B * 128), dim3(256), 0, stream>>>(Wq, bq, Wk, bk, Wv, bv,
                                                          x, y, Qt, KtW, Vws);
    attn_kernel4<<<dim3(B * 64), dim3(512), 0, stream>>>(Qt, KtW, Vws, x, gamma, out);
}

// Round 13
// 142.943 us; speedup vs baseline: 1.4175x; 1.4175x over previous
//
#include <hip/hip_runtime.h>
#include <math.h>

// Problem constants
constexpr int B  = 8;
constexpr int C  = 256;
constexpr int C8 = 32;
constexpr int L  = 2048;

typedef short v8s  __attribute__((ext_vector_type(8)));   // 8 bf16 (4 VGPRs)
typedef float f32x4 __attribute__((ext_vector_type(4)));  // MFMA accumulator

#define MF(a,b,c) __builtin_amdgcn_mfma_f32_16x16x32_bf16((a),(b),(c),0,0,0)

// round-to-nearest-even fp32 -> bf16 (as ushort); inputs finite here
__device__ inline unsigned short f2bf(float f) {
    unsigned u = __builtin_bit_cast(unsigned, f);
    u += 0x7fffu + ((u >> 16) & 1u);
    return (unsigned short)(u >> 16);
}
__device__ inline unsigned packbf(float a, float b) {
    return (unsigned)f2bf(a) | ((unsigned)f2bf(b) << 16);
}

// Raw barrier WITHOUT vmcnt drain: LDS ops visible, global loads stay in
// flight across it (the whole point of the pipeline).
__device__ inline void pbar() {
    __builtin_amdgcn_sched_barrier(0);
    asm volatile("s_waitcnt lgkmcnt(0)" ::: "memory");
    __builtin_amdgcn_s_barrier();
    __builtin_amdgcn_sched_barrier(0);
}

// ---------------------------------------------------------------------------
// W pre-convert: Wall[320][256] bf16 = rows 0-31 Wq, 32-63 Wk, 64-319 Wv.
// ---------------------------------------------------------------------------
__global__ __launch_bounds__(256)
void wcvt_kernel(const float* __restrict__ Wq, const float* __restrict__ Wk,
                 const float* __restrict__ Wv, unsigned short* __restrict__ Wall) {
    int i = blockIdx.x * 256 + threadIdx.x;   // grid 320
    int row = i >> 8, col = i & 255;
    float v = (row < 32) ? Wq[row * 256 + col]
            : (row < 64) ? Wk[(row - 32) * 256 + col]
                         : Wv[(size_t)(row - 64) * 256 + col];
    Wall[i] = f2bf(v);
}

// ---------------------------------------------------------------------------
// Fused Q/K/V projection. Grid 256 = (b, 64-wide l tile), 256 thr (4 waves),
// 1 block/CU. LDS: x,y tiles [l][c'] bf16, 16B-chunk XOR swizzle (^row&31).
// Wave w owns 5 output 16-row tiles (k5=0: Q/K; 1..4: V) x 4 l-subtiles.
// 160 MFMAs/wave. W loads bf16 from Wall (L2-resident, shared by all blocks).
// ---------------------------------------------------------------------------
__global__ __launch_bounds__(256, 1)
void proj_kernel4(const unsigned short* __restrict__ Wall,
                  const float* __restrict__ bq, const float* __restrict__ bk,
                  const float* __restrict__ bv,
                  const float* __restrict__ x,  const float* __restrict__ y,
                  unsigned short* __restrict__ Qt, unsigned short* __restrict__ Kt,
                  unsigned short* __restrict__ V) {
    const int blk  = blockIdx.x;
    const int b    = blk >> 5;            // 32 l-tiles per batch
    const int l0   = (blk & 31) * 64;
    const int t    = threadIdx.x;
    const int lane = t & 63;
    const int w    = t >> 6;              // 0..3
    const int g    = lane >> 4;           // 0..3
    const int l15  = lane & 15;

    __shared__ __align__(16) unsigned short xt[64][256];   // 32 KB
    __shared__ __align__(16) unsigned short yt[64][256];   // 32 KB

    const float* xb = x + (size_t)b * C * L;
    const float* yb = y + (size_t)b * C * L;

    // ---- stage: fp32 global -> bf16 LDS, transposed + chunk-swizzled ----
#pragma unroll
    for (int r = 0; r < 16; ++r) {
        int v  = t + 256 * r;             // 0..4095
        int c  = v >> 4;                  // input channel 0..255
        int l4 = (v & 15) * 4;            // l offset 0..60
        float4 xv = *(const float4*)(xb + (size_t)c * L + l0 + l4);
        float4 yv = *(const float4*)(yb + (size_t)c * L + l0 + l4);
        float xa[4] = {xv.x, xv.y, xv.z, xv.w};
        float ya[4] = {yv.x, yv.y, yv.z, yv.w};
#pragma unroll
        for (int i = 0; i < 4; ++i) {
            int row = l4 + i;
            int idx = (((c >> 3) ^ (row & 31)) << 3) | (c & 7);
            xt[row][idx] = f2bf(xa[i]);
            yt[row][idx] = f2bf(ya[i]);
        }
    }
    __syncthreads();

    f32x4 acc[5][4];
#pragma unroll
    for (int k5 = 0; k5 < 5; ++k5)
#pragma unroll
        for (int jt = 0; jt < 4; ++jt) { f32x4 z = {0.f,0.f,0.f,0.f}; acc[k5][jt] = z; }

#pragma unroll
    for (int kk = 0; kk < 8; ++kk) {
        v8s af[5];
#pragma unroll
        for (int k5 = 0; k5 < 5; ++k5) {
            int rowsel = (k5 == 0) ? ((w < 2 ? 0 : 32) + (w & 1) * 16)
                                   : 64 + (w + 4 * (k5 - 1)) * 16;
            af[k5] = *(const v8s*)(Wall + (size_t)(rowsel + l15) * 256 + kk * 32 + 8 * g);
        }
#pragma unroll
        for (int jt = 0; jt < 4; ++jt) {
            int row  = jt * 16 + l15;
            int boff = row * 256 + (((4 * kk + g) ^ (row & 31)) << 3);
            v8s by = *(const v8s*)(&yt[0][0] + boff);
            v8s bsel = by;
            if (w < 2) bsel = *(const v8s*)(&xt[0][0] + boff);
            acc[0][jt] = MF(af[0], bsel, acc[0][jt]);
#pragma unroll
            for (int k5 = 1; k5 < 5; ++k5)
                acc[k5][jt] = MF(af[k5], by, acc[k5][jt]);
        }
    }

    // ---- epilogue: bias + store bf16 ----
    {   // k5 = 0: Q or K, transposed store [b][l][32]
        int clbase = (w & 1) * 16;
        const float* bias = (w < 2) ? bq : bk;
        unsigned short* dst = (w < 2) ? Qt : Kt;
        float4 b4 = *(const float4*)(bias + clbase + 4 * g);
#pragma unroll
        for (int jt = 0; jt < 4; ++jt) {
            int l = l0 + jt * 16 + l15;
            unsigned* dp = (unsigned*)(dst + ((size_t)b * L + l) * C8 + clbase + 4 * g);
            dp[0] = packbf(acc[0][jt][0] + b4.x, acc[0][jt][1] + b4.y);
            dp[1] = packbf(acc[0][jt][2] + b4.z, acc[0][jt][3] + b4.w);
        }
    }
#pragma unroll
    for (int k5 = 1; k5 < 5; ++k5) {
        int cl0 = (w + 4 * (k5 - 1)) * 16 + 4 * g;
        float4 b4 = *(const float4*)(bv + cl0);
        float barr[4] = {b4.x, b4.y, b4.z, b4.w};
#pragma unroll
        for (int jt = 0; jt < 4; ++jt) {
            int l = l0 + jt * 16 + l15;
#pragma unroll
            for (int r = 0; r < 4; ++r)
                V[((size_t)b * C + cl0 + r) * L + l] = f2bf(acc[k5][jt][r] + barr[r]);
        }
    }
}

// ---------------------------------------------------------------------------
// Single-pass attention, ITILE=64, raw-barrier software pipeline.
// Grid 256 = (b, 64-row i-tile), XCD swizzle (batch-per-XCD L2 residency),
// 512 thr = 8 waves, 1 block/CU.
// Step s (j-tile 128): QK(s) [4 MFMA, E_T=mfma(K,Q)], PV(s-1) [32 MFMA,
// P from LDS, V from regs filled at step s-1 - loads cross the raw barrier
// in flight], exp/pack -> P[s&1], issue V(s)/K(s+1). 17 pbar() total.
// P tile [64][128] bf16, 16B-chunk XOR swizzle (^l15), double-buffered.
// ---------------------------------------------------------------------------
__device__ __forceinline__ void attn_step(
    int S, bool loadk, const v8s qf[4], v8s* VFC, v8s* VFN, v8s KFC, v8s& KFN,
    f32x4 acc[2][4], float sA[4], unsigned short (*Pt)[64 * 128],
    const unsigned short* Kb, const unsigned short* Vb,
    int w, int g, int l15) {
    const int jb = S * 128;
    f32x4 zz = {0.f, 0.f, 0.f, 0.f};
    // QK(S)
    f32x4 e0 = MF(KFC, qf[0], zz);
    f32x4 e1 = MF(KFC, qf[1], zz);
    f32x4 e2 = MF(KFC, qf[2], zz);
    f32x4 e3 = MF(KFC, qf[3], zz);
    // PV(S-1): P rows 16*i2+l15, V from VFC (in regs)
    const char* prd = (const char*)&Pt[(S - 1) & 1][0];
#pragma unroll
    for (int kk = 0; kk < 4; ++kk) {
        const int co = ((4 * kk + g) ^ l15) << 4;
        v8s p0 = *(const v8s*)(prd + (l15)      * 256 + co);
        v8s p1 = *(const v8s*)(prd + (16 + l15) * 256 + co);
        v8s p2 = *(const v8s*)(prd + (32 + l15) * 256 + co);
        v8s p3 = *(const v8s*)(prd + (48 + l15) * 256 + co);
        acc[0][0] = MF(VFC[kk], p0, acc[0][0]);
        acc[0][1] = MF(VFC[kk], p1, acc[0][1]);
        acc[0][2] = MF(VFC[kk], p2, acc[0][2]);
        acc[0][3] = MF(VFC[kk], p3, acc[0][3]);
        acc[1][0] = MF(VFC[4 + kk], p0, acc[1][0]);
        acc[1][1] = MF(VFC[4 + kk], p1, acc[1][1]);
        acc[1][2] = MF(VFC[4 + kk], p2, acc[1][2]);
        acc[1][3] = MF(VFC[4 + kk], p3, acc[1][3]);
    }
    // exp -> bf16 -> P[S&1]; running sums
    char* pwr = (char*)&Pt[S & 1][0];
    const int wco = (((2 * w + (g >> 1)) ^ l15) << 4) + (g & 1) * 8;
    {
        float p0 = __expf(e0[0]), p1 = __expf(e0[1]), p2 = __expf(e0[2]), p3 = __expf(e0[3]);
        sA[0] += (p0 + p1) + (p2 + p3);
        unsigned* d = (unsigned*)(pwr + (l15) * 256 + wco);
        d[0] = packbf(p0, p1); d[1] = packbf(p2, p3);
    }
    {
        float p0 = __expf(e1[0]), p1 = __expf(e1[1]), p2 = __expf(e1[2]), p3 = __expf(e1[3]);
        sA[1] += (p0 + p1) + (p2 + p3);
        unsigned* d = (unsigned*)(pwr + (16 + l15) * 256 + wco);
        d[0] = packbf(p0, p1); d[1] = packbf(p2, p3);
    }
    {
        float p0 = __expf(e2[0]), p1 = __expf(e2[1]), p2 = __expf(e2[2]), p3 = __expf(e2[3]);
        sA[2] += (p0 + p1) + (p2 + p3);
        unsigned* d = (unsigned*)(pwr + (32 + l15) * 256 + wco);
        d[0] = packbf(p0, p1); d[1] = packbf(p2, p3);
    }
    {
        float p0 = __expf(e3[0]), p1 = __expf(e3[1]), p2 = __expf(e3[2]), p3 = __expf(e3[3]);
        sA[3] += (p0 + p1) + (p2 + p3);
        unsigned* d = (unsigned*)(pwr + (48 + l15) * 256 + wco);
        d[0] = packbf(p0, p1); d[1] = packbf(p2, p3);
    }
    // issue V(S) -> VFN (consumed next step, stays in flight across pbar)
#pragma unroll
    for (int ct = 0; ct < 2; ++ct)
#pragma unroll
        for (int kk = 0; kk < 4; ++kk)
            VFN[ct * 4 + kk] = *(const v8s*)(Vb + (size_t)(w * 32 + ct * 16 + l15) * L
                                             + jb + kk * 32 + 8 * g);
    if (loadk)
        KFN = *(const v8s*)(Kb + (size_t)(jb + 128 + w * 16 + l15) * C8 + 8 * g);
    pbar();
}

__global__ __launch_bounds__(512, 2)
void attn_kernel5(const unsigned short* __restrict__ Qt,   // [B][L][32] bf16
                  const unsigned short* __restrict__ Kt,   // [B][L][32] bf16
                  const unsigned short* __restrict__ Vw,   // [B][C][L] bf16
                  const float* __restrict__ x,
                  const float* __restrict__ gamma,
                  float* __restrict__ out) {
    const int d       = blockIdx.x;
    const int logical = (d & 7) * 32 + (d >> 3);   // XCD k -> batch k
    const int b       = logical >> 5;
    const int i0      = (logical & 31) * 64;
    const int t    = threadIdx.x;
    const int lane = t & 63;
    const int w    = t >> 6;              // 0..7
    const int g    = lane >> 4;           // 0..3
    const int l15  = lane & 15;

    __shared__ __align__(16) unsigned short Pt[2][64 * 128];  // 32 KB
    __shared__ float redS[64][33];
    __shared__ float Sf[64];

    const unsigned short* Qb = Qt + (size_t)b * L * C8;
    const unsigned short* Kb = Kt + (size_t)b * L * C8;
    const unsigned short* Vb = Vw + (size_t)b * C * L;

    v8s qf[4];
#pragma unroll
    for (int i2 = 0; i2 < 4; ++i2)
        qf[i2] = *(const v8s*)(Qb + (size_t)(i0 + i2 * 16 + l15) * C8 + 8 * g);

    f32x4 acc[2][4];
#pragma unroll
    for (int ct = 0; ct < 2; ++ct)
#pragma unroll
        for (int i2 = 0; i2 < 4; ++i2) { f32x4 z = {0.f,0.f,0.f,0.f}; acc[ct][i2] = z; }
    float sA[4] = {0.f, 0.f, 0.f, 0.f};

    v8s vfA[8], vfB[8], kfA, kfB;

    // ---- prologue: step 0 (no PV) ----
    kfA = *(const v8s*)(Kb + (size_t)(w * 16 + l15) * C8 + 8 * g);
    {
        f32x4 zz = {0.f, 0.f, 0.f, 0.f};
        f32x4 e0 = MF(kfA, qf[0], zz);
        f32x4 e1 = MF(kfA, qf[1], zz);
        f32x4 e2 = MF(kfA, qf[2], zz);
        f32x4 e3 = MF(kfA, qf[3], zz);
        char* pwr = (char*)&Pt[0][0];
        const int wco = (((2 * w + (g >> 1)) ^ l15) << 4) + (g & 1) * 8;
        f32x4 ee[4] = {e0, e1, e2, e3};
#pragma unroll
        for (int i2 = 0; i2 < 4; ++i2) {
            float p0 = __expf(ee[i2][0]), p1 = __expf(ee[i2][1]);
            float p2 = __expf(ee[i2][2]), p3 = __expf(ee[i2][3]);
            sA[i2] += (p0 + p1) + (p2 + p3);
            unsigned* dd = (unsigned*)(pwr + (i2 * 16 + l15) * 256 + wco);
            dd[0] = packbf(p0, p1); dd[1] = packbf(p2, p3);
        }
#pragma unroll
        for (int ct = 0; ct < 2; ++ct)
#pragma unroll
            for (int kk = 0; kk < 4; ++kk)
                vfA[ct * 4 + kk] = *(const v8s*)(Vb + (size_t)(w * 32 + ct * 16 + l15) * L
                                                 + kk * 32 + 8 * g);
        kfB = *(const v8s*)(Kb + (size_t)(128 + w * 16 + l15) * C8 + 8 * g);
        pbar();
    }

    // ---- main loop: steps 1..14 (double body), then step 15 ----
    for (int s = 1; s <= 13; s += 2) {
        attn_step(s,     true, qf, vfA, vfB, kfB, kfA, acc, sA, Pt, Kb, Vb, w, g, l15);
        attn_step(s + 1, true, qf, vfB, vfA, kfA, kfB, acc, sA, Pt, Kb, Vb, w, g, l15);
    }
    attn_step(15, false, qf, vfA, vfB, kfB, kfA, acc, sA, Pt, Kb, Vb, w, g, l15);

    // ---- epilogue PV(15): P[1], vfB ----
    {
        const char* prd = (const char*)&Pt[1][0];
#pragma unroll
        for (int kk = 0; kk < 4; ++kk) {
            const int co = ((4 * kk + g) ^ l15) << 4;
            v8s p0 = *(const v8s*)(prd + (l15)      * 256 + co);
            v8s p1 = *(const v8s*)(prd + (16 + l15) * 256 + co);
            v8s p2 = *(const v8s*)(prd + (32 + l15) * 256 + co);
            v8s p3 = *(const v8s*)(prd + (48 + l15) * 256 + co);
            acc[0][0] = MF(vfB[kk], p0, acc[0][0]);
            acc[0][1] = MF(vfB[kk], p1, acc[0][1]);
            acc[0][2] = MF(vfB[kk], p2, acc[0][2]);
            acc[0][3] = MF(vfB[kk], p3, acc[0][3]);
            acc[1][0] = MF(vfB[4 + kk], p0, acc[1][0]);
            acc[1][1] = MF(vfB[4 + kk], p1, acc[1][1]);
            acc[1][2] = MF(vfB[4 + kk], p2, acc[1][2]);
            acc[1][3] = MF(vfB[4 + kk], p3, acc[1][3]);
        }
    }

    // ---- row-sum combine: 32 partials per row ----
#pragma unroll
    for (int i2 = 0; i2 < 4; ++i2)
        redS[i2 * 16 + l15][w * 4 + g] = sA[i2];
    __syncthreads();
    if (t < 64) {
        float S = 0.f;
#pragma unroll
        for (int p = 0; p < 32; ++p) S += redS[t][p];
        Sf[t] = 1.f / S;
    }
    __syncthreads();

    // ---- epilogue: out = x + gamma * acc / S ----
    const float gam = gamma[0];
#pragma unroll
    for (int ct = 0; ct < 2; ++ct)
#pragma unroll
        for (int i2 = 0; i2 < 4; ++i2) {
            const float inv = Sf[i2 * 16 + l15];
#pragma unroll
            for (int r = 0; r < 4; ++r) {
                int c = w * 32 + ct * 16 + 4 * g + r;   // D row -> channel
                int i = i0 + i2 * 16 + l15;             // D col -> position
                size_t off = ((size_t)b * C + c) * L + i;
                out[off] = x[off] + gam * inv * acc[ct][i2][r];
            }
        }
}

// ---------------------------------------------------------------------------
extern "C" void kernel_launch(void* const* d_in, const int* in_sizes, int n_in,
                              void* d_out, int out_size, void* d_ws, size_t ws_size,
                              hipStream_t stream) {
    const float* x     = (const float*)d_in[0];
    const float* y     = (const float*)d_in[1];
    const float* Wq    = (const float*)d_in[2];
    const float* bq    = (const float*)d_in[3];
    const float* Wk    = (const float*)d_in[4];
    const float* bk    = (const float*)d_in[5];
    const float* Wv    = (const float*)d_in[6];
    const float* bv    = (const float*)d_in[7];
    const float* gamma = (const float*)d_in[8];
    float* out = (float*)d_out;

    unsigned short* wsu  = (unsigned short*)d_ws;
    unsigned short* Qt   = wsu;                    // 524288 bf16 (1 MB)
    unsigned short* KtW  = wsu + 524288;           // 524288 bf16 (1 MB)
    unsigned short* Vws  = wsu + 1048576;          // 4194304 bf16 (8 MB)
    unsigned short* Wall = wsu + 5242880;          // 81920 bf16 (160 KB)

    wcvt_kernel<<<dim3(320), dim3(256), 0, stream>>>(Wq, Wk, Wv, Wall);
    proj_kernel4<<<dim3(B * 32), dim3(256), 0, stream>>>(Wall, bq, bk, bv,
                                                         x, y, Qt, KtW, Vws);
    attn_kernel5<<<dim3(B * 32), dim3(512), 0, stream>>>(Qt, KtW, Vws, x, gamma, out);
}